// Round 15
// baseline (507.705 us; speedup 1.0000x reference)
//
#include <hip/hip_runtime.h>
#include <math.h>

constexpr int CB  = 8;       // batch
constexpr int CN  = 4096;    // tokens
constexpr int CC  = 640;     // channels
constexpr int CNH = 5;       // heads
constexpr int CHD = 128;     // head dim
constexpr int CM  = CB * CN; // 32768 rows
constexpr float CEPS = 1e-6f;
constexpr int NCH = 8;       // token chunks for kv2 partials

typedef __attribute__((ext_vector_type(8))) short bf16x8;
typedef __attribute__((ext_vector_type(4))) float f32x4;

typedef __attribute__((address_space(1))) const unsigned int gas_u32;
typedef __attribute__((address_space(3))) unsigned int las_u32;

__device__ __forceinline__ void gload16(const void* g, void* l) {
    __builtin_amdgcn_global_load_lds((gas_u32*)g, (las_u32*)l, 16, 0, 0);
}

__device__ __forceinline__ short f2bf(float x) {
    unsigned u = __float_as_uint(x);
    unsigned r = (u + 0x7fffu + ((u >> 16) & 1u)) >> 16;   // RNE, finite data
    return (short)r;
}
__device__ __forceinline__ float b2f(unsigned short u) {
    return __uint_as_float(((unsigned)u) << 16);
}

__device__ __forceinline__ void cvt8(const float* __restrict__ s, unsigned short* __restrict__ d) {
    float4 f0 = *(const float4*)s, f1 = *(const float4*)(s + 4);
    bf16x8 h;
    h[0]=f2bf(f0.x); h[1]=f2bf(f0.y); h[2]=f2bf(f0.z); h[3]=f2bf(f0.w);
    h[4]=f2bf(f1.x); h[5]=f2bf(f1.y); h[6]=f2bf(f1.z); h[7]=f2bf(f1.w);
    *(bf16x8*)d = h;
}

// ---- merged prep: softplus(scale) + cvt of Wq, Wkv, Wproj (disjoint outputs) ----
__global__ __launch_bounds__(256) void prep_weights(const float* __restrict__ scale,
                                                    const float* __restrict__ Wq,
                                                    const float* __restrict__ Wkv,
                                                    const float* __restrict__ Wproj,
                                                    float* __restrict__ sc,
                                                    unsigned short* __restrict__ Wqbf,
                                                    unsigned short* __restrict__ Wkvbf,
                                                    unsigned short* __restrict__ Wprojbf) {
    const int gid = blockIdx.x * 256 + threadIdx.x;
    if (gid < CC) sc[gid] = log1pf(expf(scale[gid]));
    const int NQ = CC * CC / 8;          // 51200 chunks
    const int NKV = 2 * CC * CC / 8;     // 102400
    const int total = NQ + NKV + NQ;     // 204800
    const int stride = gridDim.x * 256;
    for (int c = gid; c < total; c += stride) {
        if (c < NQ)            cvt8(Wq    + (size_t)c * 8,            Wqbf    + (size_t)c * 8);
        else if (c < NQ + NKV) cvt8(Wkv   + (size_t)(c - NQ) * 8,     Wkvbf   + (size_t)(c - NQ) * 8);
        else                   cvt8(Wproj + (size_t)(c - NQ - NKV) * 8, Wprojbf + (size_t)(c - NQ - NKV) * 8);
    }
}

// ---- merged cvt of x1 and x2 -> bf16 (one launch) ----
__global__ __launch_bounds__(256) void cvt_x12(const float* __restrict__ x1,
                                               const float* __restrict__ x2,
                                               unsigned short* __restrict__ x1bf,
                                               unsigned short* __restrict__ x2bf,
                                               int n8) {
    int i = blockIdx.x * 256 + threadIdx.x;
    const int stride = gridDim.x * 256;
    for (; i < 2 * n8; i += stride) {
        if (i < n8) cvt8(x1 + (size_t)i * 8,        x1bf + (size_t)i * 8);
        else        cvt8(x2 + (size_t)(i - n8) * 8, x2bf + (size_t)(i - n8) * 8);
    }
}

// ------- bf16 MFMA GEMM: C[M,N] = A[M,K]*B[N,K]^T (+bias), bf16 in, bf16/f32 out -------
// 128x128 tile, BK=32, 4 waves, double-buffered LDS, global_load_lds(16B) w/ pre-swizzled src.
// XCD-AWARE SWIZZLE (T1). Requires gridDim.y (m-panels) % 8 == 0.
template<bool BIAS, bool OUTBF>
__global__ __launch_bounds__(256) void gemm_bf16b(const unsigned short* __restrict__ Abf,
                                                  const unsigned short* __restrict__ Bbf,
                                                  void* __restrict__ Co,
                                                  const float* __restrict__ bias,
                                                  int Kr, int Nr) {
    __shared__ unsigned short lA[2][4096];
    __shared__ unsigned short lB[2][4096];
    const int t  = threadIdx.x;
    const int npan = gridDim.x;                    // N/128
    const int mper = gridDim.y >> 3;               // m-panels per XCD
    const int wg   = blockIdx.y * npan + blockIdx.x;
    const int xcd  = wg & 7;
    const int j    = wg >> 3;
    const int m0 = (xcd * mper + j / npan) * 128;
    const int n0 = (j % npan) * 128;
    const int l  = t & 63, w = t >> 6, wr = w >> 1, wc = w & 1;

    const int cp0 = w * 64 + l;
    const int cp1 = cp0 + 256;
    const int s0 = cp0 ^ (((cp0 >> 2) & 7) ^ ((cp0 >> 4) & 1));
    const int s1 = cp1 ^ (((cp1 >> 2) & 7) ^ ((cp1 >> 4) & 1));
    const size_t gA0 = (size_t)(m0 + (s0 >> 2)) * Kr + (s0 & 3) * 8;
    const size_t gA1 = (size_t)(m0 + (s1 >> 2)) * Kr + (s1 & 3) * 8;
    const size_t gB0 = (size_t)(n0 + (s0 >> 2)) * Kr + (s0 & 3) * 8;
    const size_t gB1 = (size_t)(n0 + (s1 >> 2)) * Kr + (s1 & 3) * 8;
    const int dA0 = w * 512;
    const int dA1 = 2048 + w * 512;

    const int offA = ((wr * 64 + (l & 15)) * 64 + (l >> 4) * 16) ^ ((l & 7) << 4);
    const int offB = ((wc * 64 + (l & 15)) * 64 + (l >> 4) * 16) ^ ((l & 7) << 4);

    f32x4 acc[4][4];
    #pragma unroll
    for (int i = 0; i < 4; ++i)
        #pragma unroll
        for (int j2 = 0; j2 < 4; ++j2) acc[i][j2] = (f32x4){0.f, 0.f, 0.f, 0.f};

    gload16(Abf + gA0, &lA[0][dA0]);
    gload16(Abf + gA1, &lA[0][dA1]);
    gload16(Bbf + gB0, &lB[0][dA0]);
    gload16(Bbf + gB1, &lB[0][dA1]);
    __syncthreads();

    int cur = 0;
    for (int k0 = 0; k0 < Kr; k0 += 32) {
        if (k0 + 32 < Kr) {
            const int nb = cur ^ 1;
            gload16(Abf + gA0 + k0 + 32, &lA[nb][dA0]);
            gload16(Abf + gA1 + k0 + 32, &lA[nb][dA1]);
            gload16(Bbf + gB0 + k0 + 32, &lB[nb][dA0]);
            gload16(Bbf + gB1 + k0 + 32, &lB[nb][dA1]);
        }
        bf16x8 af[4], bfv[4];
        #pragma unroll
        for (int i = 0; i < 4; ++i) {
            af[i]  = *(const bf16x8*)((const char*)&lA[cur][0] + offA + i * 1024);
            bfv[i] = *(const bf16x8*)((const char*)&lB[cur][0] + offB + i * 1024);
        }
        #pragma unroll
        for (int i = 0; i < 4; ++i)
            #pragma unroll
            for (int j2 = 0; j2 < 4; ++j2)
                acc[i][j2] = __builtin_amdgcn_mfma_f32_16x16x32_bf16(af[i], bfv[j2], acc[i][j2], 0, 0, 0);
        __syncthreads();
        cur ^= 1;
    }

    #pragma unroll
    for (int j2 = 0; j2 < 4; ++j2) {
        const int n = n0 + wc * 64 + j2 * 16 + (l & 15);
        const float bv = BIAS ? bias[n] : 0.f;
        #pragma unroll
        for (int i = 0; i < 4; ++i) {
            const int m = m0 + wr * 64 + i * 16 + (l >> 4) * 4;
            #pragma unroll
            for (int r = 0; r < 4; ++r) {
                float val = acc[i][j2][r] + bv;
                if (OUTBF) ((unsigned short*)Co)[(size_t)(m + r) * Nr + n] = (unsigned short)f2bf(val);
                else       ((float*)Co)[(size_t)(m + r) * Nr + n] = val;
            }
        }
    }
}

// ------- per-row focused transform: one row per WAVE, shfl-only reduce -------
__global__ __launch_bounds__(256) void rowtrans2(const unsigned short* __restrict__ kq,
                                                 const float* __restrict__ pos,
                                                 const float* __restrict__ sc,
                                                 unsigned short* __restrict__ qt,
                                                 unsigned short* __restrict__ kt) {
    const int w = threadIdx.x >> 6, l = threadIdx.x & 63;
    const int m = blockIdx.x * 4 + w;
    const int n = m & (CN - 1);
    const unsigned short* rowk = kq + (size_t)m * 1280;
    const unsigned short* rowq = rowk + 640;
    float qv[10], kv[10];
    float s2q = 0.f, s6q = 0.f, s2k = 0.f, s6k = 0.f;
    #pragma unroll
    for (int j = 0; j < 10; ++j) {
        const int c = l + 64 * j;
        const float scv = sc[c];
        float qq = (fmaxf(b2f(rowq[c]), 0.f) + CEPS) / scv;
        float kk = (fmaxf(b2f(rowk[c]) + pos[(size_t)n * CC + c], 0.f) + CEPS) / scv;
        qv[j] = qq; kv[j] = kk;
        const float q2 = qq * qq, k2 = kk * kk;
        s2q += q2; s6q += q2 * q2 * q2;
        s2k += k2; s6k += k2 * k2 * k2;
    }
    #pragma unroll
    for (int o = 32; o > 0; o >>= 1) {
        s2q += __shfl_xor(s2q, o);
        s6q += __shfl_xor(s6q, o);
        s2k += __shfl_xor(s2k, o);
        s6k += __shfl_xor(s6k, o);
    }
    const float qmul = sqrtf(s2q) / sqrtf(s6q);
    const float kmul = sqrtf(s2k) / sqrtf(s6k);
    #pragma unroll
    for (int j = 0; j < 10; ++j) {
        const int c = l + 64 * j;
        qt[(size_t)m * CC + c] = (unsigned short)f2bf(qv[j] * qv[j] * qv[j] * qmul);
        kt[(size_t)m * CC + c] = (unsigned short)f2bf(kv[j] * kv[j] * kv[j] * kmul);
    }
}

// ------- kv2 partials, QUADRANT split: per (nc, bh, q): 64x64 of K^T V over 512 rows -------
__global__ __launch_bounds__(256) void kv2_partial(const unsigned short* __restrict__ kt,
                                                   const unsigned short* __restrict__ vb,
                                                   float* __restrict__ kv2p,
                                                   float* __restrict__ ksmp) {
    const int nc = blockIdx.x, bh = blockIdx.y, q = blockIdx.z;
    const int qc = q & 1, qd = q >> 1;
    const int b = bh / CNH, h = bh % CNH;
    __shared__ float ks[32][68];
    __shared__ float vs[32][68];
    const int t = threadIdx.x;
    const int tx = t & 15, ty = t >> 4;
    float acc[4][4];
    #pragma unroll
    for (int i = 0; i < 4; ++i)
        #pragma unroll
        for (int j = 0; j < 4; ++j) acc[i][j] = 0.f;
    float ksacc = 0.f;
    const size_t mbase = (size_t)b * CN + (size_t)nc * 512;
    const int cofK = h * CHD + qc * 64;
    const int cofV = h * CHD + qd * 64;
    const int token = t >> 3, c8 = (t & 7) * 8;
    for (int tile = 0; tile < 16; ++tile) {
        const int nt0 = tile * 32;
        __syncthreads();
        {
            const size_t r = (mbase + nt0 + token) * CC;
            bf16x8 hk = *(const bf16x8*)(kt + r + cofK + c8);
            bf16x8 hv = *(const bf16x8*)(vb + r + cofV + c8);
            float4 k0, k1, v0, v1;
            k0.x=b2f(hk[0]); k0.y=b2f(hk[1]); k0.z=b2f(hk[2]); k0.w=b2f(hk[3]);
            k1.x=b2f(hk[4]); k1.y=b2f(hk[5]); k1.z=b2f(hk[6]); k1.w=b2f(hk[7]);
            v0.x=b2f(hv[0]); v0.y=b2f(hv[1]); v0.z=b2f(hv[2]); v0.w=b2f(hv[3]);
            v1.x=b2f(hv[4]); v1.y=b2f(hv[5]); v1.z=b2f(hv[6]); v1.w=b2f(hv[7]);
            *(float4*)&ks[token][c8]     = k0;
            *(float4*)&ks[token][c8 + 4] = k1;
            *(float4*)&vs[token][c8]     = v0;
            *(float4*)&vs[token][c8 + 4] = v1;
        }
        __syncthreads();
        #pragma unroll 4
        for (int nn = 0; nn < 32; ++nn) {
            float4 av = *(const float4*)&ks[nn][ty * 4];
            float4 bv = *(const float4*)&vs[nn][tx * 4];
            float a[4] = {av.x, av.y, av.z, av.w};
            float bb[4] = {bv.x, bv.y, bv.z, bv.w};
            #pragma unroll
            for (int i = 0; i < 4; ++i)
                #pragma unroll
                for (int j = 0; j < 4; ++j)
                    acc[i][j] = fmaf(a[i], bb[j], acc[i][j]);
        }
        if (qd == 0 && t < 64) {
            #pragma unroll
            for (int nn = 0; nn < 32; ++nn) ksacc += ks[nn][t];
        }
    }
    float* outp = kv2p + (((size_t)bh * NCH + nc) * 4 + q) * 4096;
    #pragma unroll
    for (int i = 0; i < 4; ++i) {
        float4 o;
        o.x = acc[i][0]; o.y = acc[i][1]; o.z = acc[i][2]; o.w = acc[i][3];
        *(float4*)&outp[(ty * 4 + i) * 64 + tx * 4] = o;
    }
    if (qd == 0 && t < 64)
        ksmp[(((size_t)bh * NCH + nc) * 2 + qc) * 64 + t] = ksacc;
}

// ------- reduce partials; emit kv2^T as bf16 [d][c] + ksum f32 -------
__global__ __launch_bounds__(256) void kv2_reduce(const float* __restrict__ kv2p,
                                                  const float* __restrict__ ksmp,
                                                  unsigned short* __restrict__ kv2bf,
                                                  float* __restrict__ ksm) {
    const int bh = blockIdx.x, t = threadIdx.x;
    for (int o = t; o < 16384; o += 256) {
        const int d = o >> 7, c = o & 127;
        const int q = (d >> 6) * 2 + (c >> 6);
        float s = 0.f;
        #pragma unroll
        for (int nc = 0; nc < NCH; ++nc)
            s += kv2p[(((size_t)bh * NCH + nc) * 4 + q) * 4096 + (c & 63) * 64 + (d & 63)];
        kv2bf[(size_t)bh * 16384 + o] = (unsigned short)f2bf(s);
    }
    if (t < 128) {
        float s = 0.f;
        #pragma unroll
        for (int nc = 0; nc < NCH; ++nc)
            s += ksmp[(((size_t)bh * NCH + nc) * 2 + (t >> 6)) * 64 + (t & 63)];
        ksm[(size_t)bh * 128 + t] = s;
    }
}

// ------- attention out via MFMA: att = (q@kv2)*z, bf16 in/out -------
__global__ __launch_bounds__(256) void attn_mfma(const unsigned short* __restrict__ qt,
                                                 const unsigned short* __restrict__ kv2bf,
                                                 const float* __restrict__ ksm,
                                                 unsigned short* __restrict__ attb) {
    const int nb = blockIdx.x, bh = blockIdx.y;
    const int b = bh / CNH, h = bh % CNH;
    __shared__ short lQ[16384];    // 128 x 128 bf16, swizzled
    __shared__ short lKV[16384];   // [d][c] bf16, swizzled
    __shared__ float zs[128];
    const int t = threadIdx.x;
    const int l = t & 63, w = t >> 6, wr = w >> 1, wc = w & 1;
    const size_t m0 = (size_t)b * CN + (size_t)nb * 128;

    const int srow0 = t >> 4;      // 0..15
    const int c16   = t & 15;      // 16B chunk within row
    float kreg[8];
    {
        const float* kp = ksm + (size_t)bh * 128 + c16 * 8;
        float4 k0 = *(const float4*)kp, k1 = *(const float4*)(kp + 4);
        kreg[0]=k0.x; kreg[1]=k0.y; kreg[2]=k0.z; kreg[3]=k0.w;
        kreg[4]=k1.x; kreg[5]=k1.y; kreg[6]=k1.z; kreg[7]=k1.w;
    }
    #pragma unroll
    for (int p = 0; p < 8; ++p) {
        const int row = srow0 + p * 16;
        const int st = (row * 256 + c16 * 16) ^ ((row & 7) << 4);
        bf16x8 hq = *(const bf16x8*)(qt + (m0 + row) * CC + h * CHD + c16 * 8);
        *(bf16x8*)((char*)lQ + st) = hq;
        float zp = 0.f;
        #pragma unroll
        for (int j = 0; j < 8; ++j) zp = fmaf(b2f((unsigned short)hq[j]), kreg[j], zp);
        zp += __shfl_xor(zp, 1);
        zp += __shfl_xor(zp, 2);
        zp += __shfl_xor(zp, 4);
        zp += __shfl_xor(zp, 8);
        if (c16 == 0) zs[row] = 1.f / (zp + CEPS);
        bf16x8 hk = *(const bf16x8*)(kv2bf + (size_t)bh * 16384 + row * 128 + c16 * 8);
        *(bf16x8*)((char*)lKV + st) = hk;
    }
    __syncthreads();

    const int baseA = (wr * 64 + (l & 15)) * 256 + ((l >> 4) << 4);
    const int baseB = (wc * 64 + (l & 15)) * 256 + ((l >> 4) << 4);
    const int xorv  = (l & 7) << 4;
    f32x4 acc[4][4];
    #pragma unroll
    for (int i = 0; i < 4; ++i)
        #pragma unroll
        for (int j = 0; j < 4; ++j) acc[i][j] = (f32x4){0.f, 0.f, 0.f, 0.f};

    #pragma unroll
    for (int kk = 0; kk < 4; ++kk) {
        bf16x8 af[4], bv[4];
        #pragma unroll
        for (int i = 0; i < 4; ++i) {
            af[i] = *(const bf16x8*)((const char*)lQ  + (((baseA + kk * 64) ^ xorv) + i * 4096));
            bv[i] = *(const bf16x8*)((const char*)lKV + (((baseB + kk * 64) ^ xorv) + i * 4096));
        }
        #pragma unroll
        for (int i = 0; i < 4; ++i)
            #pragma unroll
            for (int j = 0; j < 4; ++j)
                acc[i][j] = __builtin_amdgcn_mfma_f32_16x16x32_bf16(af[i], bv[j], acc[i][j], 0, 0, 0);
    }

    #pragma unroll
    for (int i = 0; i < 4; ++i) {
        const int mBase = wr * 64 + i * 16 + (l >> 4) * 4;
        float zv[4];
        #pragma unroll
        for (int r = 0; r < 4; ++r) zv[r] = zs[mBase + r];
        #pragma unroll
        for (int j = 0; j < 4; ++j) {
            const int n = wc * 64 + j * 16 + (l & 15);
            unsigned short* op = attb + (m0 + mBase) * CC + h * CHD + n;
            #pragma unroll
            for (int r = 0; r < 4; ++r)
                op[(size_t)r * CC] = (unsigned short)f2bf(acc[i][j][r] * zv[r]);
        }
    }
}

// ------- LDS-tiled 5x5 depthwise conv: x = att + conv(v) + bias, bf16 in/out -------
__global__ __launch_bounds__(256) void dwconv2(const unsigned short* __restrict__ vb,
                                               const unsigned short* __restrict__ attb,
                                               const float* __restrict__ w,
                                               const float* __restrict__ bias,
                                               unsigned short* __restrict__ xb) {
    const int yt = blockIdx.x;      // 0..7
    const int dq = blockIdx.y;      // 0..3
    const int bh = blockIdx.z;      // 0..39
    const int b = bh / CNH, h = bh % CNH;
    __shared__ unsigned short vt[12 * 68 * 32];
    const int t = threadIdx.x;
    const int y0 = yt * 8;
    const size_t rowbase = (size_t)b * CN;
    const int cbase = h * CHD + dq * 32;
    for (int c = t; c < 3264; c += 256) {
        int pos = c >> 2, d8 = (c & 3) * 8;
        int ly = pos / 68, lx = pos - ly * 68;
        int yy = y0 - 2 + ly, xx = lx - 2;
        bf16x8 val = (bf16x8){0,0,0,0,0,0,0,0};
        if (yy >= 0 && yy < 64 && xx >= 0 && xx < 64)
            val = *(const bf16x8*)(vb + (rowbase + yy * 64 + xx) * CC + cbase + d8);
        *(bf16x8*)(vt + pos * 32 + d8) = val;
    }
    __syncthreads();
    const int dp = t & 15;
    const int xg = t >> 4;
    const int d0 = dq * 32 + dp * 2;            // head-dim channel in [0,128)
    float wr0[25], wr1[25];
    #pragma unroll
    for (int i = 0; i < 25; ++i) {
        wr0[i] = w[d0 * 25 + i];
        wr1[i] = w[(d0 + 1) * 25 + i];
    }
    const float bv0 = bias[d0], bv1 = bias[d0 + 1];
    const int x0 = xg * 4;
    for (int oy = 0; oy < 8; ++oy) {
        float a0[4] = {bv0, bv0, bv0, bv0}, a1[4] = {bv1, bv1, bv1, bv1};
        #pragma unroll
        for (int dy = 0; dy < 5; ++dy) {
            const unsigned short* rp = vt + ((oy + dy) * 68 + x0) * 32 + dp * 2;
            float v0[8], v1[8];
            #pragma unroll
            for (int j = 0; j < 8; ++j) {
                unsigned pr = *(const unsigned*)(rp + j * 32);
                v0[j] = __uint_as_float(pr << 16);
                v1[j] = __uint_as_float(pr & 0xffff0000u);
            }
            #pragma unroll
            for (int dx = 0; dx < 5; ++dx) {
                const float w0 = wr0[dy * 5 + dx], w1 = wr1[dy * 5 + dx];
                #pragma unroll
                for (int xo = 0; xo < 4; ++xo) {
                    a0[xo] = fmaf(w0, v0[xo + dx], a0[xo]);
                    a1[xo] = fmaf(w1, v1[xo + dx], a1[xo]);
                }
            }
        }
        #pragma unroll
        for (int xo = 0; xo < 4; ++xo) {
            size_t g = (rowbase + (y0 + oy) * 64 + x0 + xo) * CC + cbase + dp * 2;
            unsigned ap = *(const unsigned*)(attb + g);
            float at0 = __uint_as_float(ap << 16);
            float at1 = __uint_as_float(ap & 0xffff0000u);
            unsigned short o0 = (unsigned short)f2bf(a0[xo] + at0);
            unsigned short o1 = (unsigned short)f2bf(a1[xo] + at1);
            *(unsigned*)(xb + g) = (unsigned)o0 | ((unsigned)o1 << 16);
        }
    }
}

extern "C" void kernel_launch(void* const* d_in, const int* in_sizes, int n_in,
                              void* d_out, int out_size, void* d_ws, size_t ws_size,
                              hipStream_t stream) {
    (void)in_sizes; (void)n_in; (void)out_size; (void)ws_size;
    const float* x1    = (const float*)d_in[0];
    const float* x2    = (const float*)d_in[1];
    const float* Wq    = (const float*)d_in[2];
    const float* Wkv   = (const float*)d_in[3];
    const float* Wproj = (const float*)d_in[4];
    const float* bproj = (const float*)d_in[5];
    const float* dwcw  = (const float*)d_in[6];
    const float* dwcb  = (const float*)d_in[7];
    const float* scale = (const float*)d_in[8];
    const float* pos   = (const float*)d_in[9];
    float* out = (float*)d_out;

    const size_t MC = (size_t)CM * CC;   // 20,971,520 elems
    unsigned short* ws16 = (unsigned short*)d_ws;
    // region A [0, MC): x1bf -> kv2p(f32, 21MB) -> attbf
    unsigned short* x1bf  = ws16;
    float*          kv2p  = (float*)ws16;
    unsigned short* attbf = ws16;
    // region B [MC, 2MC): x2bf -> ktbf -> xbf
    unsigned short* x2bf = ws16 + MC;
    unsigned short* ktbf = x2bf;
    unsigned short* xbf  = x2bf;
    // region C [2MC, 3MC): vbf (live through dwconv2)
    unsigned short* vbf  = ws16 + 2 * MC;
    // region D [3MC, 4MC): qtbf
    unsigned short* qtbf = ws16 + 3 * MC;
    // tail
    unsigned short* kv2bf = ws16 + 4 * MC;                          // 40*16384 bf16
    float* ksmp = (float*)(kv2bf + (size_t)40 * 16384);             // 40*8*2*64 f32
    float* ksm  = ksmp + (size_t)40 * NCH * 128;                    // 40*128
    float* scb  = ksm + (size_t)40 * 128;                           // 640
    unsigned short* Wqbf    = (unsigned short*)(scb + 640);         // 640*640
    unsigned short* Wkvbf   = Wqbf + (size_t)CC * CC;               // 1280*640
    unsigned short* Wprojbf = Wkvbf + (size_t)2 * CC * CC;          // 640*640
    // kq GEMM output lives in d_out as bf16 [M][1280] (exactly fills it)
    unsigned short* kqbf = (unsigned short*)d_out;

    hipLaunchKernelGGL(prep_weights, dim3(256), dim3(256), 0, stream,
                       scale, Wq, Wkv, Wproj, scb, Wqbf, Wkvbf, Wprojbf);
    hipLaunchKernelGGL(cvt_x12, dim3(2048), dim3(256), 0, stream,
                       x1, x2, x1bf, x2bf, (int)(MC / 8));

    // v = x2 @ Wq^T
    hipLaunchKernelGGL((gemm_bf16b<false, true>), dim3(CC/128, CM/128), dim3(256), 0, stream,
                       x2bf, Wqbf, (void*)vbf, (const float*)nullptr, CC, CC);
    // [k|q] = x1 @ Wkv^T
    hipLaunchKernelGGL((gemm_bf16b<false, true>), dim3(1280/128, CM/128), dim3(256), 0, stream,
                       x1bf, Wkvbf, (void*)kqbf, (const float*)nullptr, CC, 1280);
    hipLaunchKernelGGL(rowtrans2, dim3(CM/4), dim3(256), 0, stream, kqbf, pos, scb, qtbf, ktbf);
    hipLaunchKernelGGL(kv2_partial, dim3(NCH, 40, 4), dim3(256), 0, stream, ktbf, vbf, kv2p, ksmp);
    hipLaunchKernelGGL(kv2_reduce, dim3(40), dim3(256), 0, stream, kv2p, ksmp, kv2bf, ksm);
    hipLaunchKernelGGL(attn_mfma, dim3(CN/128, 40), dim3(256), 0, stream, qtbf, kv2bf, ksm, attbf);
    hipLaunchKernelGGL(dwconv2, dim3(8, 4, 40), dim3(256), 0, stream, vbf, attbf, dwcw, dwcb, xbf);
    // out = x @ Wproj^T + b
    hipLaunchKernelGGL((gemm_bf16b<true, false>), dim3(CC/128, CM/128), dim3(256), 0, stream,
                       xbf, Wprojbf, (void*)out, bproj, CC, CC);
}

// Round 16
// 476.990 us; speedup vs baseline: 1.0644x; 1.0644x over previous
//
#include <hip/hip_runtime.h>
#include <math.h>

constexpr int CB  = 8;       // batch
constexpr int CN  = 4096;    // tokens
constexpr int CC  = 640;     // channels
constexpr int CNH = 5;       // heads
constexpr int CHD = 128;     // head dim
constexpr int CM  = CB * CN; // 32768 rows
constexpr float CEPS = 1e-6f;
constexpr int NCH = 8;       // token chunks for kv2 partials

typedef __attribute__((ext_vector_type(8))) short bf16x8;
typedef __attribute__((ext_vector_type(4))) float f32x4;

typedef __attribute__((address_space(1))) const unsigned int gas_u32;
typedef __attribute__((address_space(3))) unsigned int las_u32;

__device__ __forceinline__ void gload16(const void* g, void* l) {
    __builtin_amdgcn_global_load_lds((gas_u32*)g, (las_u32*)l, 16, 0, 0);
}

__device__ __forceinline__ short f2bf(float x) {
    unsigned u = __float_as_uint(x);
    unsigned r = (u + 0x7fffu + ((u >> 16) & 1u)) >> 16;   // RNE, finite data
    return (short)r;
}
__device__ __forceinline__ float b2f(unsigned short u) {
    return __uint_as_float(((unsigned)u) << 16);
}

__device__ __forceinline__ void cvt8(const float* __restrict__ s, unsigned short* __restrict__ d) {
    float4 f0 = *(const float4*)s, f1 = *(const float4*)(s + 4);
    bf16x8 h;
    h[0]=f2bf(f0.x); h[1]=f2bf(f0.y); h[2]=f2bf(f0.z); h[3]=f2bf(f0.w);
    h[4]=f2bf(f1.x); h[5]=f2bf(f1.y); h[6]=f2bf(f1.z); h[7]=f2bf(f1.w);
    *(bf16x8*)d = h;
}

// ---- merged prep: softplus(scale) + cvt of Wq, Wkv, Wproj (disjoint outputs) ----
__global__ __launch_bounds__(256) void prep_weights(const float* __restrict__ scale,
                                                    const float* __restrict__ Wq,
                                                    const float* __restrict__ Wkv,
                                                    const float* __restrict__ Wproj,
                                                    float* __restrict__ sc,
                                                    unsigned short* __restrict__ Wqbf,
                                                    unsigned short* __restrict__ Wkvbf,
                                                    unsigned short* __restrict__ Wprojbf) {
    const int gid = blockIdx.x * 256 + threadIdx.x;
    if (gid < CC) sc[gid] = log1pf(expf(scale[gid]));
    const int NQ = CC * CC / 8;          // 51200 chunks
    const int NKV = 2 * CC * CC / 8;     // 102400
    const int total = NQ + NKV + NQ;     // 204800
    const int stride = gridDim.x * 256;
    for (int c = gid; c < total; c += stride) {
        if (c < NQ)            cvt8(Wq    + (size_t)c * 8,            Wqbf    + (size_t)c * 8);
        else if (c < NQ + NKV) cvt8(Wkv   + (size_t)(c - NQ) * 8,     Wkvbf   + (size_t)(c - NQ) * 8);
        else                   cvt8(Wproj + (size_t)(c - NQ - NKV) * 8, Wprojbf + (size_t)(c - NQ - NKV) * 8);
    }
}

// ---- merged cvt of x1 and x2 -> bf16 (one launch) ----
__global__ __launch_bounds__(256) void cvt_x12(const float* __restrict__ x1,
                                               const float* __restrict__ x2,
                                               unsigned short* __restrict__ x1bf,
                                               unsigned short* __restrict__ x2bf,
                                               int n8) {
    int i = blockIdx.x * 256 + threadIdx.x;
    const int stride = gridDim.x * 256;
    for (; i < 2 * n8; i += stride) {
        if (i < n8) cvt8(x1 + (size_t)i * 8,        x1bf + (size_t)i * 8);
        else        cvt8(x2 + (size_t)(i - n8) * 8, x2bf + (size_t)(i - n8) * 8);
    }
}

// ------- GEMM core: C[M,N] = A[M,K]*B[N,K]^T (+bias), bf16 in -------
// 128x128 tile, BK=32, 4 waves, double-buffered LDS, global_load_lds(16B) w/
// pre-swizzled src, XCD-aware swizzle (T1). wg/npan/mper supplied by caller.
template<bool BIAS, bool OUTBF>
__device__ __forceinline__ void gemm_core(const unsigned short* __restrict__ Abf,
                                          const unsigned short* __restrict__ Bbf,
                                          void* __restrict__ Co,
                                          const float* __restrict__ bias,
                                          int Kr, int Nr, int wg, int npan, int mper) {
    __shared__ unsigned short lA[2][4096];
    __shared__ unsigned short lB[2][4096];
    const int t  = threadIdx.x;
    const int xcd  = wg & 7;
    const int j    = wg >> 3;
    const int m0 = (xcd * mper + j / npan) * 128;
    const int n0 = (j % npan) * 128;
    const int l  = t & 63, w = t >> 6, wr = w >> 1, wc = w & 1;

    const int cp0 = w * 64 + l;
    const int cp1 = cp0 + 256;
    const int s0 = cp0 ^ (((cp0 >> 2) & 7) ^ ((cp0 >> 4) & 1));
    const int s1 = cp1 ^ (((cp1 >> 2) & 7) ^ ((cp1 >> 4) & 1));
    const size_t gA0 = (size_t)(m0 + (s0 >> 2)) * Kr + (s0 & 3) * 8;
    const size_t gA1 = (size_t)(m0 + (s1 >> 2)) * Kr + (s1 & 3) * 8;
    const size_t gB0 = (size_t)(n0 + (s0 >> 2)) * Kr + (s0 & 3) * 8;
    const size_t gB1 = (size_t)(n0 + (s1 >> 2)) * Kr + (s1 & 3) * 8;
    const int dA0 = w * 512;
    const int dA1 = 2048 + w * 512;

    const int offA = ((wr * 64 + (l & 15)) * 64 + (l >> 4) * 16) ^ ((l & 7) << 4);
    const int offB = ((wc * 64 + (l & 15)) * 64 + (l >> 4) * 16) ^ ((l & 7) << 4);

    f32x4 acc[4][4];
    #pragma unroll
    for (int i = 0; i < 4; ++i)
        #pragma unroll
        for (int j2 = 0; j2 < 4; ++j2) acc[i][j2] = (f32x4){0.f, 0.f, 0.f, 0.f};

    gload16(Abf + gA0, &lA[0][dA0]);
    gload16(Abf + gA1, &lA[0][dA1]);
    gload16(Bbf + gB0, &lB[0][dA0]);
    gload16(Bbf + gB1, &lB[0][dA1]);
    __syncthreads();

    int cur = 0;
    for (int k0 = 0; k0 < Kr; k0 += 32) {
        if (k0 + 32 < Kr) {
            const int nb = cur ^ 1;
            gload16(Abf + gA0 + k0 + 32, &lA[nb][dA0]);
            gload16(Abf + gA1 + k0 + 32, &lA[nb][dA1]);
            gload16(Bbf + gB0 + k0 + 32, &lB[nb][dA0]);
            gload16(Bbf + gB1 + k0 + 32, &lB[nb][dA1]);
        }
        bf16x8 af[4], bfv[4];
        #pragma unroll
        for (int i = 0; i < 4; ++i) {
            af[i]  = *(const bf16x8*)((const char*)&lA[cur][0] + offA + i * 1024);
            bfv[i] = *(const bf16x8*)((const char*)&lB[cur][0] + offB + i * 1024);
        }
        #pragma unroll
        for (int i = 0; i < 4; ++i)
            #pragma unroll
            for (int j2 = 0; j2 < 4; ++j2)
                acc[i][j2] = __builtin_amdgcn_mfma_f32_16x16x32_bf16(af[i], bfv[j2], acc[i][j2], 0, 0, 0);
        __syncthreads();
        cur ^= 1;
    }

    #pragma unroll
    for (int j2 = 0; j2 < 4; ++j2) {
        const int n = n0 + wc * 64 + j2 * 16 + (l & 15);
        const float bv = BIAS ? bias[n] : 0.f;
        #pragma unroll
        for (int i = 0; i < 4; ++i) {
            const int m = m0 + wr * 64 + i * 16 + (l >> 4) * 4;
            #pragma unroll
            for (int r = 0; r < 4; ++r) {
                float val = acc[i][j2][r] + bv;
                if (OUTBF) ((unsigned short*)Co)[(size_t)(m + r) * Nr + n] = (unsigned short)f2bf(val);
                else       ((float*)Co)[(size_t)(m + r) * Nr + n] = val;
            }
        }
    }
}

// ---- fused v-GEMM + kq-GEMM: one dispatch, blocks 0..1279 = v, 1280..3839 = kq ----
__global__ __launch_bounds__(256) void gemm_vkq(const unsigned short* __restrict__ x2bf,
                                                const unsigned short* __restrict__ Wqbf,
                                                unsigned short* __restrict__ vbf,
                                                const unsigned short* __restrict__ x1bf,
                                                const unsigned short* __restrict__ Wkvbf,
                                                unsigned short* __restrict__ kqbf) {
    const int id = blockIdx.x;
    if (id < 1280) {
        gemm_core<false, true>(x2bf, Wqbf, (void*)vbf, nullptr, CC, CC, id, 5, 32);
    } else {
        gemm_core<false, true>(x1bf, Wkvbf, (void*)kqbf, nullptr, CC, 1280, id - 1280, 10, 32);
    }
}

// ---- projection GEMM: out = x @ Wproj^T + b (f32 out) ----
__global__ __launch_bounds__(256) void gemm_proj(const unsigned short* __restrict__ xbf,
                                                 const unsigned short* __restrict__ Wprojbf,
                                                 float* __restrict__ out,
                                                 const float* __restrict__ bproj) {
    gemm_core<true, false>(xbf, Wprojbf, (void*)out, bproj, CC, CC,
                           blockIdx.y * gridDim.x + blockIdx.x, gridDim.x, gridDim.y >> 3);
}

// ------- per-row focused transform: one row per WAVE, shfl-only reduce -------
__global__ __launch_bounds__(256) void rowtrans2(const unsigned short* __restrict__ kq,
                                                 const float* __restrict__ pos,
                                                 const float* __restrict__ sc,
                                                 unsigned short* __restrict__ qt,
                                                 unsigned short* __restrict__ kt) {
    const int w = threadIdx.x >> 6, l = threadIdx.x & 63;
    const int m = blockIdx.x * 4 + w;
    const int n = m & (CN - 1);
    const unsigned short* rowk = kq + (size_t)m * 1280;
    const unsigned short* rowq = rowk + 640;
    float qv[10], kv[10];
    float s2q = 0.f, s6q = 0.f, s2k = 0.f, s6k = 0.f;
    #pragma unroll
    for (int j = 0; j < 10; ++j) {
        const int c = l + 64 * j;
        const float scv = sc[c];
        float qq = (fmaxf(b2f(rowq[c]), 0.f) + CEPS) / scv;
        float kk = (fmaxf(b2f(rowk[c]) + pos[(size_t)n * CC + c], 0.f) + CEPS) / scv;
        qv[j] = qq; kv[j] = kk;
        const float q2 = qq * qq, k2 = kk * kk;
        s2q += q2; s6q += q2 * q2 * q2;
        s2k += k2; s6k += k2 * k2 * k2;
    }
    #pragma unroll
    for (int o = 32; o > 0; o >>= 1) {
        s2q += __shfl_xor(s2q, o);
        s6q += __shfl_xor(s6q, o);
        s2k += __shfl_xor(s2k, o);
        s6k += __shfl_xor(s6k, o);
    }
    const float qmul = sqrtf(s2q) / sqrtf(s6q);
    const float kmul = sqrtf(s2k) / sqrtf(s6k);
    #pragma unroll
    for (int j = 0; j < 10; ++j) {
        const int c = l + 64 * j;
        qt[(size_t)m * CC + c] = (unsigned short)f2bf(qv[j] * qv[j] * qv[j] * qmul);
        kt[(size_t)m * CC + c] = (unsigned short)f2bf(kv[j] * kv[j] * kv[j] * kmul);
    }
}

// ------- kv2 partials, QUADRANT split: per (nc, bh, q): 64x64 of K^T V over 512 rows -------
__global__ __launch_bounds__(256) void kv2_partial(const unsigned short* __restrict__ kt,
                                                   const unsigned short* __restrict__ vb,
                                                   float* __restrict__ kv2p,
                                                   float* __restrict__ ksmp) {
    const int nc = blockIdx.x, bh = blockIdx.y, q = blockIdx.z;
    const int qc = q & 1, qd = q >> 1;
    const int b = bh / CNH, h = bh % CNH;
    __shared__ float ks[32][68];
    __shared__ float vs[32][68];
    const int t = threadIdx.x;
    const int tx = t & 15, ty = t >> 4;
    float acc[4][4];
    #pragma unroll
    for (int i = 0; i < 4; ++i)
        #pragma unroll
        for (int j = 0; j < 4; ++j) acc[i][j] = 0.f;
    float ksacc = 0.f;
    const size_t mbase = (size_t)b * CN + (size_t)nc * 512;
    const int cofK = h * CHD + qc * 64;
    const int cofV = h * CHD + qd * 64;
    const int token = t >> 3, c8 = (t & 7) * 8;
    for (int tile = 0; tile < 16; ++tile) {
        const int nt0 = tile * 32;
        __syncthreads();
        {
            const size_t r = (mbase + nt0 + token) * CC;
            bf16x8 hk = *(const bf16x8*)(kt + r + cofK + c8);
            bf16x8 hv = *(const bf16x8*)(vb + r + cofV + c8);
            float4 k0, k1, v0, v1;
            k0.x=b2f(hk[0]); k0.y=b2f(hk[1]); k0.z=b2f(hk[2]); k0.w=b2f(hk[3]);
            k1.x=b2f(hk[4]); k1.y=b2f(hk[5]); k1.z=b2f(hk[6]); k1.w=b2f(hk[7]);
            v0.x=b2f(hv[0]); v0.y=b2f(hv[1]); v0.z=b2f(hv[2]); v0.w=b2f(hv[3]);
            v1.x=b2f(hv[4]); v1.y=b2f(hv[5]); v1.z=b2f(hv[6]); v1.w=b2f(hv[7]);
            *(float4*)&ks[token][c8]     = k0;
            *(float4*)&ks[token][c8 + 4] = k1;
            *(float4*)&vs[token][c8]     = v0;
            *(float4*)&vs[token][c8 + 4] = v1;
        }
        __syncthreads();
        #pragma unroll 4
        for (int nn = 0; nn < 32; ++nn) {
            float4 av = *(const float4*)&ks[nn][ty * 4];
            float4 bv = *(const float4*)&vs[nn][tx * 4];
            float a[4] = {av.x, av.y, av.z, av.w};
            float bb[4] = {bv.x, bv.y, bv.z, bv.w};
            #pragma unroll
            for (int i = 0; i < 4; ++i)
                #pragma unroll
                for (int j = 0; j < 4; ++j)
                    acc[i][j] = fmaf(a[i], bb[j], acc[i][j]);
        }
        if (qd == 0 && t < 64) {
            #pragma unroll
            for (int nn = 0; nn < 32; ++nn) ksacc += ks[nn][t];
        }
    }
    float* outp = kv2p + (((size_t)bh * NCH + nc) * 4 + q) * 4096;
    #pragma unroll
    for (int i = 0; i < 4; ++i) {
        float4 o;
        o.x = acc[i][0]; o.y = acc[i][1]; o.z = acc[i][2]; o.w = acc[i][3];
        *(float4*)&outp[(ty * 4 + i) * 64 + tx * 4] = o;
    }
    if (qd == 0 && t < 64)
        ksmp[(((size_t)bh * NCH + nc) * 2 + qc) * 64 + t] = ksacc;
}

// ------- reduce partials; emit kv2^T as bf16 [d][c] + ksum f32 -------
__global__ __launch_bounds__(256) void kv2_reduce(const float* __restrict__ kv2p,
                                                  const float* __restrict__ ksmp,
                                                  unsigned short* __restrict__ kv2bf,
                                                  float* __restrict__ ksm) {
    const int bh = blockIdx.x, t = threadIdx.x;
    for (int o = t; o < 16384; o += 256) {
        const int d = o >> 7, c = o & 127;
        const int q = (d >> 6) * 2 + (c >> 6);
        float s = 0.f;
        #pragma unroll
        for (int nc = 0; nc < NCH; ++nc)
            s += kv2p[(((size_t)bh * NCH + nc) * 4 + q) * 4096 + (c & 63) * 64 + (d & 63)];
        kv2bf[(size_t)bh * 16384 + o] = (unsigned short)f2bf(s);
    }
    if (t < 128) {
        float s = 0.f;
        #pragma unroll
        for (int nc = 0; nc < NCH; ++nc)
            s += ksmp[(((size_t)bh * NCH + nc) * 2 + (t >> 6)) * 64 + (t & 63)];
        ksm[(size_t)bh * 128 + t] = s;
    }
}

// ------- attention out via MFMA: att = (q@kv2)*z, bf16 in/out -------
__global__ __launch_bounds__(256) void attn_mfma(const unsigned short* __restrict__ qt,
                                                 const unsigned short* __restrict__ kv2bf,
                                                 const float* __restrict__ ksm,
                                                 unsigned short* __restrict__ attb) {
    const int nb = blockIdx.x, bh = blockIdx.y;
    const int b = bh / CNH, h = bh % CNH;
    __shared__ short lQ[16384];    // 128 x 128 bf16, swizzled
    __shared__ short lKV[16384];   // [d][c] bf16, swizzled
    __shared__ float zs[128];
    const int t = threadIdx.x;
    const int l = t & 63, w = t >> 6, wr = w >> 1, wc = w & 1;
    const size_t m0 = (size_t)b * CN + (size_t)nb * 128;

    const int srow0 = t >> 4;      // 0..15
    const int c16   = t & 15;      // 16B chunk within row
    float kreg[8];
    {
        const float* kp = ksm + (size_t)bh * 128 + c16 * 8;
        float4 k0 = *(const float4*)kp, k1 = *(const float4*)(kp + 4);
        kreg[0]=k0.x; kreg[1]=k0.y; kreg[2]=k0.z; kreg[3]=k0.w;
        kreg[4]=k1.x; kreg[5]=k1.y; kreg[6]=k1.z; kreg[7]=k1.w;
    }
    #pragma unroll
    for (int p = 0; p < 8; ++p) {
        const int row = srow0 + p * 16;
        const int st = (row * 256 + c16 * 16) ^ ((row & 7) << 4);
        bf16x8 hq = *(const bf16x8*)(qt + (m0 + row) * CC + h * CHD + c16 * 8);
        *(bf16x8*)((char*)lQ + st) = hq;
        float zp = 0.f;
        #pragma unroll
        for (int j = 0; j < 8; ++j) zp = fmaf(b2f((unsigned short)hq[j]), kreg[j], zp);
        zp += __shfl_xor(zp, 1);
        zp += __shfl_xor(zp, 2);
        zp += __shfl_xor(zp, 4);
        zp += __shfl_xor(zp, 8);
        if (c16 == 0) zs[row] = 1.f / (zp + CEPS);
        bf16x8 hk = *(const bf16x8*)(kv2bf + (size_t)bh * 16384 + row * 128 + c16 * 8);
        *(bf16x8*)((char*)lKV + st) = hk;
    }
    __syncthreads();

    const int baseA = (wr * 64 + (l & 15)) * 256 + ((l >> 4) << 4);
    const int baseB = (wc * 64 + (l & 15)) * 256 + ((l >> 4) << 4);
    const int xorv  = (l & 7) << 4;
    f32x4 acc[4][4];
    #pragma unroll
    for (int i = 0; i < 4; ++i)
        #pragma unroll
        for (int j = 0; j < 4; ++j) acc[i][j] = (f32x4){0.f, 0.f, 0.f, 0.f};

    #pragma unroll
    for (int kk = 0; kk < 4; ++kk) {
        bf16x8 af[4], bv[4];
        #pragma unroll
        for (int i = 0; i < 4; ++i) {
            af[i] = *(const bf16x8*)((const char*)lQ  + (((baseA + kk * 64) ^ xorv) + i * 4096));
            bv[i] = *(const bf16x8*)((const char*)lKV + (((baseB + kk * 64) ^ xorv) + i * 4096));
        }
        #pragma unroll
        for (int i = 0; i < 4; ++i)
            #pragma unroll
            for (int j = 0; j < 4; ++j)
                acc[i][j] = __builtin_amdgcn_mfma_f32_16x16x32_bf16(af[i], bv[j], acc[i][j], 0, 0, 0);
    }

    #pragma unroll
    for (int i = 0; i < 4; ++i) {
        const int mBase = wr * 64 + i * 16 + (l >> 4) * 4;
        float zv[4];
        #pragma unroll
        for (int r = 0; r < 4; ++r) zv[r] = zs[mBase + r];
        #pragma unroll
        for (int j = 0; j < 4; ++j) {
            const int n = wc * 64 + j * 16 + (l & 15);
            unsigned short* op = attb + (m0 + mBase) * CC + h * CHD + n;
            #pragma unroll
            for (int r = 0; r < 4; ++r)
                op[(size_t)r * CC] = (unsigned short)f2bf(acc[i][j][r] * zv[r]);
        }
    }
}

// ------- LDS-tiled 5x5 depthwise conv: x = att + conv(v) + bias, bf16 in/out -------
__global__ __launch_bounds__(256) void dwconv2(const unsigned short* __restrict__ vb,
                                               const unsigned short* __restrict__ attb,
                                               const float* __restrict__ w,
                                               const float* __restrict__ bias,
                                               unsigned short* __restrict__ xb) {
    const int yt = blockIdx.x;      // 0..7
    const int dq = blockIdx.y;      // 0..3
    const int bh = blockIdx.z;      // 0..39
    const int b = bh / CNH, h = bh % CNH;
    __shared__ unsigned short vt[12 * 68 * 32];
    const int t = threadIdx.x;
    const int y0 = yt * 8;
    const size_t rowbase = (size_t)b * CN;
    const int cbase = h * CHD + dq * 32;
    for (int c = t; c < 3264; c += 256) {
        int pos = c >> 2, d8 = (c & 3) * 8;
        int ly = pos / 68, lx = pos - ly * 68;
        int yy = y0 - 2 + ly, xx = lx - 2;
        bf16x8 val = (bf16x8){0,0,0,0,0,0,0,0};
        if (yy >= 0 && yy < 64 && xx >= 0 && xx < 64)
            val = *(const bf16x8*)(vb + (rowbase + yy * 64 + xx) * CC + cbase + d8);
        *(bf16x8*)(vt + pos * 32 + d8) = val;
    }
    __syncthreads();
    const int dp = t & 15;
    const int xg = t >> 4;
    const int d0 = dq * 32 + dp * 2;            // head-dim channel in [0,128)
    float wr0[25], wr1[25];
    #pragma unroll
    for (int i = 0; i < 25; ++i) {
        wr0[i] = w[d0 * 25 + i];
        wr1[i] = w[(d0 + 1) * 25 + i];
    }
    const float bv0 = bias[d0], bv1 = bias[d0 + 1];
    const int x0 = xg * 4;
    for (int oy = 0; oy < 8; ++oy) {
        float a0[4] = {bv0, bv0, bv0, bv0}, a1[4] = {bv1, bv1, bv1, bv1};
        #pragma unroll
        for (int dy = 0; dy < 5; ++dy) {
            const unsigned short* rp = vt + ((oy + dy) * 68 + x0) * 32 + dp * 2;
            float v0[8], v1[8];
            #pragma unroll
            for (int j = 0; j < 8; ++j) {
                unsigned pr = *(const unsigned*)(rp + j * 32);
                v0[j] = __uint_as_float(pr << 16);
                v1[j] = __uint_as_float(pr & 0xffff0000u);
            }
            #pragma unroll
            for (int dx = 0; dx < 5; ++dx) {
                const float w0 = wr0[dy * 5 + dx], w1 = wr1[dy * 5 + dx];
                #pragma unroll
                for (int xo = 0; xo < 4; ++xo) {
                    a0[xo] = fmaf(w0, v0[xo + dx], a0[xo]);
                    a1[xo] = fmaf(w1, v1[xo + dx], a1[xo]);
                }
            }
        }
        #pragma unroll
        for (int xo = 0; xo < 4; ++xo) {
            size_t g = (rowbase + (y0 + oy) * 64 + x0 + xo) * CC + cbase + dp * 2;
            unsigned ap = *(const unsigned*)(attb + g);
            float at0 = __uint_as_float(ap << 16);
            float at1 = __uint_as_float(ap & 0xffff0000u);
            unsigned short o0 = (unsigned short)f2bf(a0[xo] + at0);
            unsigned short o1 = (unsigned short)f2bf(a1[xo] + at1);
            *(unsigned*)(xb + g) = (unsigned)o0 | ((unsigned)o1 << 16);
        }
    }
}

extern "C" void kernel_launch(void* const* d_in, const int* in_sizes, int n_in,
                              void* d_out, int out_size, void* d_ws, size_t ws_size,
                              hipStream_t stream) {
    (void)in_sizes; (void)n_in; (void)out_size; (void)ws_size;
    const float* x1    = (const float*)d_in[0];
    const float* x2    = (const float*)d_in[1];
    const float* Wq    = (const float*)d_in[2];
    const float* Wkv   = (const float*)d_in[3];
    const float* Wproj = (const float*)d_in[4];
    const float* bproj = (const float*)d_in[5];
    const float* dwcw  = (const float*)d_in[6];
    const float* dwcb  = (const float*)d_in[7];
    const float* scale = (const float*)d_in[8];
    const float* pos   = (const float*)d_in[9];
    float* out = (float*)d_out;

    const size_t MC = (size_t)CM * CC;   // 20,971,520 elems
    unsigned short* ws16 = (unsigned short*)d_ws;
    // region A [0, MC): x1bf -> kv2p(f32, 21MB) -> attbf
    unsigned short* x1bf  = ws16;
    float*          kv2p  = (float*)ws16;
    unsigned short* attbf = ws16;
    // region B [MC, 2MC): x2bf -> ktbf -> xbf
    unsigned short* x2bf = ws16 + MC;
    unsigned short* ktbf = x2bf;
    unsigned short* xbf  = x2bf;
    // region C [2MC, 3MC): vbf (live through dwconv2)
    unsigned short* vbf  = ws16 + 2 * MC;
    // region D [3MC, 4MC): qtbf
    unsigned short* qtbf = ws16 + 3 * MC;
    // tail
    unsigned short* kv2bf = ws16 + 4 * MC;                          // 40*16384 bf16
    float* ksmp = (float*)(kv2bf + (size_t)40 * 16384);             // 40*8*2*64 f32
    float* ksm  = ksmp + (size_t)40 * NCH * 128;                    // 40*128
    float* scb  = ksm + (size_t)40 * 128;                           // 640
    unsigned short* Wqbf    = (unsigned short*)(scb + 640);         // 640*640
    unsigned short* Wkvbf   = Wqbf + (size_t)CC * CC;               // 1280*640
    unsigned short* Wprojbf = Wkvbf + (size_t)2 * CC * CC;          // 640*640
    // kq GEMM output lives in d_out as bf16 [M][1280] (exactly fills it)
    unsigned short* kqbf = (unsigned short*)d_out;

    hipLaunchKernelGGL(prep_weights, dim3(256), dim3(256), 0, stream,
                       scale, Wq, Wkv, Wproj, scb, Wqbf, Wkvbf, Wprojbf);
    hipLaunchKernelGGL(cvt_x12, dim3(2048), dim3(256), 0, stream,
                       x1, x2, x1bf, x2bf, (int)(MC / 8));

    // v = x2 @ Wq^T  and  [k|q] = x1 @ Wkv^T  in ONE dispatch (tail overlap)
    hipLaunchKernelGGL(gemm_vkq, dim3(3840), dim3(256), 0, stream,
                       x2bf, Wqbf, vbf, x1bf, Wkvbf, kqbf);
    hipLaunchKernelGGL(rowtrans2, dim3(CM/4), dim3(256), 0, stream, kqbf, pos, scb, qtbf, ktbf);
    hipLaunchKernelGGL(kv2_partial, dim3(NCH, 40, 4), dim3(256), 0, stream, ktbf, vbf, kv2p, ksmp);
    hipLaunchKernelGGL(kv2_reduce, dim3(40), dim3(256), 0, stream, kv2p, ksmp, kv2bf, ksm);
    hipLaunchKernelGGL(attn_mfma, dim3(CN/128, 40), dim3(256), 0, stream, qtbf, kv2bf, ksm, attbf);
    hipLaunchKernelGGL(dwconv2, dim3(8, 4, 40), dim3(256), 0, stream, vbf, attbf, dwcw, dwcb, xbf);
    hipLaunchKernelGGL(gemm_proj, dim3(CC/128, CM/128), dim3(256), 0, stream,
                       xbf, Wprojbf, out, bproj);
}